// Round 3
// baseline (4713.696 us; speedup 1.0000x reference)
//
#include <hip/hip_runtime.h>
#include <hip/hip_bf16.h>
#include <stdint.h>

#define BATCH 512
#define TSTEPS 64
#define DIN 1024
#define HID 512
#define G3 1536
#define MROWS (BATCH * TSTEPS)
#define POUT 512

typedef __attribute__((ext_vector_type(8))) short bf16x8;
typedef __attribute__((ext_vector_type(4))) float f32x4;

__device__ __forceinline__ float bf2f(short s) {
  union { unsigned u; float f; } v;
  v.u = ((unsigned)(unsigned short)s) << 16;
  return v.f;
}
__device__ __forceinline__ short f2bf(float f) {
  __hip_bfloat16 h = __float2bfloat16(f);
  short s;
  __builtin_memcpy(&s, &h, 2);
  return s;
}
__device__ __forceinline__ void gload_lds16(const void* g, void* l) {
  __builtin_amdgcn_global_load_lds(
      (const __attribute__((address_space(1))) void*)g,
      (__attribute__((address_space(3))) void*)l, 16, 0, 0);
}

// ---------------------------------------------------------------------------
// transpose + fp32->bf16 cast: out[c][r] = bf16(in[r][c])  (for W_in -> Wt)
// ---------------------------------------------------------------------------
__global__ __launch_bounds__(256) void transpose_cast(const float* __restrict__ in,
                                                      short* __restrict__ out,
                                                      int R, int C) {
  __shared__ float tile[32][33];
  const int c0 = blockIdx.x * 32, r0 = blockIdx.y * 32;
  const int tx = threadIdx.x & 31, ty = threadIdx.x >> 5;
#pragma unroll
  for (int i = 0; i < 4; ++i) {
    const int r = r0 + ty + i * 8;
    tile[ty + i * 8][tx] = in[(size_t)r * C + c0 + tx];
  }
  __syncthreads();
#pragma unroll
  for (int i = 0; i < 4; ++i) {
    const int c = c0 + ty + i * 8;
    out[(size_t)c * R + r0 + tx] = f2bf(tile[tx][ty + i * 8]);
  }
}

// ---------------------------------------------------------------------------
// Pack U (fp32 [512][1536]) -> Ut2 bf16 [slice 0..31][768 pos][32 k].
// slice = half*16 + kc. Position permutation gives each wave a contiguous
// 96-col region per half with its gate triple balanced 6 tiles per slice:
//   g=0:            half0, p = w*96 + cc
//   g=1, cc<32:     half0, p = w*96 + 64 + cc
//   g=1, cc>=32:    half1, p = w*96 + (cc-32)
//   g=2:            half1, p = w*96 + 32 + cc
// ---------------------------------------------------------------------------
__global__ __launch_bounds__(256) void u_pack(const float* __restrict__ U,
                                              short* __restrict__ Ut2) {
  const int idx = blockIdx.x * 256 + threadIdx.x;  // over 512*1536
  const int c = idx % G3, k = idx / G3;
  const int g = c >> 9, j = c & 511, ww = j >> 6, cc = j & 63;
  int h, p;
  if (g == 0)      { h = 0; p = ww * 96 + cc; }
  else if (g == 1) { if (cc < 32) { h = 0; p = ww * 96 + 64 + cc; }
                     else         { h = 1; p = ww * 96 + cc - 32; } }
  else             { h = 1; p = ww * 96 + 32 + cc; }
  const int kc = k >> 5, kk = k & 31;
  Ut2[((size_t)(h * 16 + kc) * 768 + p) * 32 + kk] = f2bf(U[(size_t)k * G3 + c]);
}

// ---------------------------------------------------------------------------
// Kernel 1: XG = bf16(X @ W_in + b_in), MFMA 128x128 BK=64.
// Output layout: XG[t*512 + b][1536]  (scan-friendly: step-t slice contiguous)
// ---------------------------------------------------------------------------
__global__ __launch_bounds__(256) void gemm_xg_mfma(const float* __restrict__ X,
                                                    const short* __restrict__ Wt,
                                                    const float* __restrict__ bin,
                                                    __hip_bfloat16* __restrict__ XG) {
  __shared__ __align__(16) short As[128 * 64];
  __shared__ __align__(16) short Bs[128 * 64];
  const int tid = threadIdx.x;
  const int w = tid >> 6, l = tid & 63;
  const int lc = l & 15, lg = l >> 4;

  const int nwg = gridDim.x;
  const int wg = (blockIdx.x & 7) * (nwg >> 3) + (blockIdx.x >> 3);
  const int rt = wg & 255, ct = wg >> 8;
  const int row0 = rt * 128, col0 = ct * 128;

  const int wm = w >> 1, wn = w & 1;

  f32x4 acc[4][4];
#pragma unroll
  for (int mt = 0; mt < 4; ++mt)
#pragma unroll
    for (int nt = 0; nt < 4; ++nt) acc[mt][nt] = (f32x4){0.f, 0.f, 0.f, 0.f};

  const int tr = tid >> 3, p = tid & 7;

  for (int k0 = 0; k0 < DIN; k0 += 64) {
    float4 ar[4][2];
#pragma unroll
    for (int i = 0; i < 4; ++i) {
      const int r = i * 32 + tr;
      const int s = p ^ (r & 7);
      const float* xp = &X[(size_t)(row0 + r) * DIN + k0 + s * 8];
      ar[i][0] = *reinterpret_cast<const float4*>(xp);
      ar[i][1] = *reinterpret_cast<const float4*>(xp + 4);
    }
    __syncthreads();
#pragma unroll
    for (int i = 0; i < 4; ++i) {
      const int r = i * 32 + tr;
      bf16x8 v;
      v[0] = f2bf(ar[i][0].x); v[1] = f2bf(ar[i][0].y);
      v[2] = f2bf(ar[i][0].z); v[3] = f2bf(ar[i][0].w);
      v[4] = f2bf(ar[i][1].x); v[5] = f2bf(ar[i][1].y);
      v[6] = f2bf(ar[i][1].z); v[7] = f2bf(ar[i][1].w);
      *reinterpret_cast<bf16x8*>((char*)As + r * 128 + p * 16) = v;
    }
#pragma unroll
    for (int i = 0; i < 4; ++i) {
      const int rr = w * 32 + i * 8 + (l >> 3);
      const int pp = l & 7;
      const int s = pp ^ (rr & 7);
      gload_lds16(&Wt[(size_t)(col0 + rr) * DIN + k0 + s * 8],
                  (char*)Bs + (w * 32 + i * 8) * 128);
    }
    __syncthreads();
#pragma unroll
    for (int kc = 0; kc < 2; ++kc) {
      bf16x8 a[4], b[4];
#pragma unroll
      for (int mt = 0; mt < 4; ++mt) {
        const int R = wm * 64 + mt * 16 + lc;
        const int ch = (kc * 4 + lg) ^ (R & 7);
        a[mt] = *reinterpret_cast<const bf16x8*>((const char*)As + R * 128 + ch * 16);
      }
#pragma unroll
      for (int nt = 0; nt < 4; ++nt) {
        const int Rn = wn * 64 + nt * 16 + lc;
        const int ch = (kc * 4 + lg) ^ (Rn & 7);
        b[nt] = *reinterpret_cast<const bf16x8*>((const char*)Bs + Rn * 128 + ch * 16);
      }
#pragma unroll
      for (int mt = 0; mt < 4; ++mt)
#pragma unroll
        for (int nt = 0; nt < 4; ++nt)
          acc[mt][nt] = __builtin_amdgcn_mfma_f32_16x16x32_bf16(a[mt], b[nt],
                                                                acc[mt][nt], 0, 0, 0);
    }
  }

  float bv[4];
#pragma unroll
  for (int nt = 0; nt < 4; ++nt) bv[nt] = bin[col0 + wn * 64 + nt * 16 + lc];
#pragma unroll
  for (int mt = 0; mt < 4; ++mt) {
#pragma unroll
    for (int nt = 0; nt < 4; ++nt) {
      const int col = col0 + wn * 64 + nt * 16 + lc;
#pragma unroll
      for (int rr = 0; rr < 4; ++rr) {
        const int m = row0 + wm * 64 + mt * 16 + lg * 4 + rr;
        const size_t rowp = (size_t)(m & 63) * 512 + (m >> 6);  // [t][b] layout
        XG[rowp * G3 + col] = __float2bfloat16(acc[mt][nt][rr] + bv[nt]);
      }
    }
  }
}

// ---------------------------------------------------------------------------
// Kernel 2: GRU scan. 32 blocks x 8 waves, M=16 batches/block.
// U streamed per step as 32 slices of [768 cols][32 k] via linear
// global_load_lds into ping-pong LDS buffers; B-frags via conflict-free
// ds_read_b128; gates fully in-register (wave-local gate triples).
// ---------------------------------------------------------------------------
__global__ __launch_bounds__(512, 2) void gru_scan_mfma2(
    const __hip_bfloat16* __restrict__ XG, const short* __restrict__ Ut2,
    const float* __restrict__ brec, float* __restrict__ HT) {
  __shared__ __align__(16) short Ub[2][24576];  // 2 x 48 KB
  __shared__ __align__(16) short hS[16 * 512];  // 16 KB
  const int tid = threadIdx.x, w = tid >> 6, l = tid & 63;
  const int b0 = blockIdx.x * 16;
  const int cw = w * 64;
  const int lc = l & 15, lg = l >> 4;

  for (int i = tid; i < 16 * 512; i += 512) hS[i] = 0;

  float br[3][4];
#pragma unroll
  for (int g = 0; g < 3; ++g)
#pragma unroll
    for (int t4 = 0; t4 < 4; ++t4) br[g][t4] = brec[g * 512 + cw + t4 * 16 + lc];

  // prologue: stage slice 0 into Ub[0]
  {
    const short* src = Ut2 + (size_t)0 * 24576 + w * 3072 + l * 8;
    short* dst = &Ub[0][w * 3072];
#pragma unroll
    for (int i = 0; i < 6; ++i) gload_lds16(src + i * 512, dst + i * 512);
  }
  __syncthreads();

  for (int t = 0; t < TSTEPS; ++t) {
    // A-frags: h rows (batch = lc), k = kc*32 + lg*8
    bf16x8 af[16];
#pragma unroll
    for (int kc = 0; kc < 16; ++kc)
      af[kc] = *reinterpret_cast<const bf16x8*>(hS + lc * 512 + kc * 32 + lg * 8);

    // xg loads for this step (small, L2-hot window)
    short xgs[3][4][4];
#pragma unroll
    for (int t4 = 0; t4 < 4; ++t4)
#pragma unroll
      for (int r = 0; r < 4; ++r) {
        const __hip_bfloat16* xp =
            XG + ((size_t)t * 512 + b0 + lg * 4 + r) * G3 + cw + t4 * 16 + lc;
        xgs[0][t4][r] = *(const short*)(xp);
        xgs[1][t4][r] = *(const short*)(xp + 512);
        xgs[2][t4][r] = *(const short*)(xp + 1024);
      }

    f32x4 za[3][4];
#pragma unroll
    for (int g = 0; g < 3; ++g)
#pragma unroll
      for (int t4 = 0; t4 < 4; ++t4) za[g][t4] = (f32x4){0.f, 0.f, 0.f, 0.f};

    for (int s = 0; s < 32; ++s) {
      // stage next slice into the other buffer (issue before compute)
      {
        const int sn = (s + 1) & 31;
        const short* src = Ut2 + (size_t)sn * 24576 + w * 3072 + l * 8;
        short* dst = &Ub[(s + 1) & 1][w * 3072];
#pragma unroll
        for (int i = 0; i < 6; ++i) gload_lds16(src + i * 512, dst + i * 512);
      }
      const int kc = s & 15;
      const short* B = Ub[s & 1];
      const bf16x8 a = af[kc];
      if (s < 16) {  // half 0: z tiles t4 0..3, r tiles t4 0..1
#pragma unroll
        for (int t4 = 0; t4 < 4; ++t4) {
          const int p = w * 96 + t4 * 16 + lc;
          const bf16x8 bf = *reinterpret_cast<const bf16x8*>(B + p * 32 + lg * 8);
          za[0][t4] = __builtin_amdgcn_mfma_f32_16x16x32_bf16(a, bf, za[0][t4], 0, 0, 0);
        }
#pragma unroll
        for (int t4 = 0; t4 < 2; ++t4) {
          const int p = w * 96 + 64 + t4 * 16 + lc;
          const bf16x8 bf = *reinterpret_cast<const bf16x8*>(B + p * 32 + lg * 8);
          za[1][t4] = __builtin_amdgcn_mfma_f32_16x16x32_bf16(a, bf, za[1][t4], 0, 0, 0);
        }
      } else {  // half 1: r tiles t4 2..3, h tiles t4 0..3
#pragma unroll
        for (int t4 = 2; t4 < 4; ++t4) {
          const int p = w * 96 + (t4 - 2) * 16 + lc;
          const bf16x8 bf = *reinterpret_cast<const bf16x8*>(B + p * 32 + lg * 8);
          za[1][t4] = __builtin_amdgcn_mfma_f32_16x16x32_bf16(a, bf, za[1][t4], 0, 0, 0);
        }
#pragma unroll
        for (int t4 = 0; t4 < 4; ++t4) {
          const int p = w * 96 + 32 + t4 * 16 + lc;
          const bf16x8 bf = *reinterpret_cast<const bf16x8*>(B + p * 32 + lg * 8);
          za[2][t4] = __builtin_amdgcn_mfma_f32_16x16x32_bf16(a, bf, za[2][t4], 0, 0, 0);
        }
      }
      __syncthreads();  // drains staging vmcnt; next slice ready
    }

    // gates in-register; lane holds rows lg*4+0..3 of col cw + t4*16 + lc
#pragma unroll
    for (int t4 = 0; t4 < 4; ++t4) {
      const int j = cw + t4 * 16 + lc;
#pragma unroll
      for (int r = 0; r < 4; ++r) {
        const float xz = bf2f(xgs[0][t4][r]);
        const float xr = bf2f(xgs[1][t4][r]);
        const float xh = bf2f(xgs[2][t4][r]);
        const float hz = za[0][t4][r] + br[0][t4];
        const float hr = za[1][t4][r] + br[1][t4];
        const float hh = za[2][t4][r] + br[2][t4];
        const float z = 1.f / (1.f + __expf(-(xz + hz)));
        const float rg = 1.f / (1.f + __expf(-(xr + hr)));
        const float hc = fmaxf(fmaf(rg, hh, xh), 0.f);
        const int hi = (lg * 4 + r) * 512 + j;
        const float hold = bf2f(hS[hi]);
        hS[hi] = f2bf(fmaf(z, hold - hc, hc));
      }
    }
    __syncthreads();  // h(t) visible before next step's A-frag reads
  }

  for (int i = tid; i < 16 * HID; i += 512) {
    const int R = i >> 9, j = i & 511;
    HT[(size_t)(b0 + R) * HID + j] = bf2f(hS[i]);
  }
}

// ---------------------------------------------------------------------------
// Kernel 3: out = cat(hT,hT) @ W2 + b2 == hT @ (W2_top + W2_bot) + b2
// ---------------------------------------------------------------------------
__global__ __launch_bounds__(256) void final_proj(const float* __restrict__ HT,
                                                  const float* __restrict__ W2,
                                                  const float* __restrict__ b2,
                                                  float* __restrict__ OUT) {
  const int b = blockIdx.x >> 1;
  const int pp = ((blockIdx.x & 1) << 8) + threadIdx.x;
  float acc = b2[pp];
  const float* h = &HT[(size_t)b * HID];
  for (int k = 0; k < HID; ++k)
    acc = fmaf(h[k], W2[(size_t)k * POUT + pp] + W2[(size_t)(k + HID) * POUT + pp], acc);
  OUT[(size_t)b * POUT + pp] = acc;
}

// ---------------------------------------------------------------------------
extern "C" void kernel_launch(void* const* d_in, const int* in_sizes, int n_in,
                              void* d_out, int out_size, void* d_ws,
                              size_t ws_size, hipStream_t stream) {
  const float* X    = (const float*)d_in[0];
  const float* Win  = (const float*)d_in[1];
  const float* bin  = (const float*)d_in[2];
  const float* U    = (const float*)d_in[3];
  const float* brec = (const float*)d_in[4];
  const float* W2   = (const float*)d_in[5];
  const float* b2   = (const float*)d_in[6];
  float* OUT = (float*)d_out;

  char* ws = (char*)d_ws;
  __hip_bfloat16* XG = (__hip_bfloat16*)ws;                          // 100.7 MB
  short* Wt  = (short*)(ws + (size_t)MROWS * G3 * 2);                // 3.15 MB
  short* Ut2 = (short*)(ws + (size_t)MROWS * G3 * 2 + (size_t)G3 * DIN * 2);  // 1.57 MB
  float* HT  = (float*)(ws + (size_t)MROWS * G3 * 2 + (size_t)G3 * DIN * 2 +
                        (size_t)G3 * HID * 2);                       // 1 MB

  transpose_cast<<<dim3(G3 / 32, DIN / 32), 256, 0, stream>>>(Win, Wt, DIN, G3);
  u_pack<<<(HID * G3) / 256, 256, 0, stream>>>(U, Ut2);
  gemm_xg_mfma<<<(MROWS / 128) * (G3 / 128), 256, 0, stream>>>(X, Wt, bin, XG);
  gru_scan_mfma2<<<BATCH / 16, 512, 0, stream>>>(XG, Ut2, brec, HT);
  final_proj<<<(BATCH * POUT) / 256, 256, 0, stream>>>(HT, W2, b2, OUT);
}

// Round 4
// 1477.110 us; speedup vs baseline: 3.1912x; 3.1912x over previous
//
#include <hip/hip_runtime.h>
#include <hip/hip_bf16.h>
#include <stdint.h>

#define BATCH 512
#define TSTEPS 64
#define DIN 1024
#define HID 512
#define G3 1536
#define MROWS (BATCH * TSTEPS)
#define POUT 512

typedef __attribute__((ext_vector_type(8))) short bf16x8;
typedef __attribute__((ext_vector_type(4))) float f32x4;

__device__ __forceinline__ float bf2f(short s) {
  union { unsigned u; float f; } v;
  v.u = ((unsigned)(unsigned short)s) << 16;
  return v.f;
}
__device__ __forceinline__ short f2bf(float f) {
  __hip_bfloat16 h = __float2bfloat16(f);
  short s;
  __builtin_memcpy(&s, &h, 2);
  return s;
}
__device__ __forceinline__ void gload_lds16(const void* g, void* l) {
  __builtin_amdgcn_global_load_lds(
      (const __attribute__((address_space(1))) void*)g,
      (__attribute__((address_space(3))) void*)l, 16, 0, 0);
}

// ---------------------------------------------------------------------------
// transpose + fp32->bf16 cast: out[c][r] = bf16(in[r][c])  (for W_in -> Wt)
// ---------------------------------------------------------------------------
__global__ __launch_bounds__(256) void transpose_cast(const float* __restrict__ in,
                                                      short* __restrict__ out,
                                                      int R, int C) {
  __shared__ float tile[32][33];
  const int c0 = blockIdx.x * 32, r0 = blockIdx.y * 32;
  const int tx = threadIdx.x & 31, ty = threadIdx.x >> 5;
#pragma unroll
  for (int i = 0; i < 4; ++i) {
    const int r = r0 + ty + i * 8;
    tile[ty + i * 8][tx] = in[(size_t)r * C + c0 + tx];
  }
  __syncthreads();
#pragma unroll
  for (int i = 0; i < 4; ++i) {
    const int c = c0 + ty + i * 8;
    out[(size_t)c * R + r0 + tx] = f2bf(tile[tx][ty + i * 8]);
  }
}

// ---------------------------------------------------------------------------
// Pack U (fp32 [512][1536]) -> Upk bf16 [16 cg][96 ur][64 slot][8 e], where
// ur = g*32 + cc covers gate g's cols (cg*32 + cc), and slot holds logical
// k-chunk (slot ^ (ur&7)) -- i.e. the XOR swizzle is pre-applied in global
// layout so the scan can stage it LINEARLY with global_load_lds.
// ---------------------------------------------------------------------------
__global__ __launch_bounds__(256) void u_pack2(const float* __restrict__ U,
                                               short* __restrict__ Upk) {
  const unsigned idx = blockIdx.x * 256 + threadIdx.x;  // < 786432
  const unsigned cg = idx / 49152u;
  const unsigned rem = idx - cg * 49152u;
  const unsigned ur = rem >> 9;
  const unsigned r2 = rem & 511u;
  const unsigned s = r2 >> 3, e = r2 & 7u;
  const unsigned chunk = s ^ (ur & 7u);
  const unsigned k = chunk * 8u + e;
  const unsigned g = ur >> 5, cc = ur & 31u;
  const unsigned col = g * 512u + cg * 32u + cc;
  Upk[idx] = f2bf(U[(size_t)k * G3 + col]);
}

// ---------------------------------------------------------------------------
// Kernel 1: XG = bf16(X @ W_in + b_in), MFMA 128x128 BK=64.
// Output layout: XG[t*512 + b][1536]  (scan-friendly)
// ---------------------------------------------------------------------------
__global__ __launch_bounds__(256) void gemm_xg_mfma(const float* __restrict__ X,
                                                    const short* __restrict__ Wt,
                                                    const float* __restrict__ bin,
                                                    __hip_bfloat16* __restrict__ XG) {
  __shared__ __align__(16) short As[128 * 64];
  __shared__ __align__(16) short Bs[128 * 64];
  const int tid = threadIdx.x;
  const int w = tid >> 6, l = tid & 63;
  const int lc = l & 15, lg = l >> 4;

  const int nwg = gridDim.x;
  const int wg = (blockIdx.x & 7) * (nwg >> 3) + (blockIdx.x >> 3);
  const int rt = wg & 255, ct = wg >> 8;
  const int row0 = rt * 128, col0 = ct * 128;

  const int wm = w >> 1, wn = w & 1;

  f32x4 acc[4][4];
#pragma unroll
  for (int mt = 0; mt < 4; ++mt)
#pragma unroll
    for (int nt = 0; nt < 4; ++nt) acc[mt][nt] = (f32x4){0.f, 0.f, 0.f, 0.f};

  const int tr = tid >> 3, p = tid & 7;

  for (int k0 = 0; k0 < DIN; k0 += 64) {
    float4 ar[4][2];
#pragma unroll
    for (int i = 0; i < 4; ++i) {
      const int r = i * 32 + tr;
      const int s = p ^ (r & 7);
      const float* xp = &X[(size_t)(row0 + r) * DIN + k0 + s * 8];
      ar[i][0] = *reinterpret_cast<const float4*>(xp);
      ar[i][1] = *reinterpret_cast<const float4*>(xp + 4);
    }
    __syncthreads();
#pragma unroll
    for (int i = 0; i < 4; ++i) {
      const int r = i * 32 + tr;
      bf16x8 v;
      v[0] = f2bf(ar[i][0].x); v[1] = f2bf(ar[i][0].y);
      v[2] = f2bf(ar[i][0].z); v[3] = f2bf(ar[i][0].w);
      v[4] = f2bf(ar[i][1].x); v[5] = f2bf(ar[i][1].y);
      v[6] = f2bf(ar[i][1].z); v[7] = f2bf(ar[i][1].w);
      *reinterpret_cast<bf16x8*>((char*)As + r * 128 + p * 16) = v;
    }
#pragma unroll
    for (int i = 0; i < 4; ++i) {
      const int rr = w * 32 + i * 8 + (l >> 3);
      const int pp = l & 7;
      const int s = pp ^ (rr & 7);
      gload_lds16(&Wt[(size_t)(col0 + rr) * DIN + k0 + s * 8],
                  (char*)Bs + (w * 32 + i * 8) * 128);
    }
    __syncthreads();
#pragma unroll
    for (int kc = 0; kc < 2; ++kc) {
      bf16x8 a[4], b[4];
#pragma unroll
      for (int mt = 0; mt < 4; ++mt) {
        const int R = wm * 64 + mt * 16 + lc;
        const int ch = (kc * 4 + lg) ^ (R & 7);
        a[mt] = *reinterpret_cast<const bf16x8*>((const char*)As + R * 128 + ch * 16);
      }
#pragma unroll
      for (int nt = 0; nt < 4; ++nt) {
        const int Rn = wn * 64 + nt * 16 + lc;
        const int ch = (kc * 4 + lg) ^ (Rn & 7);
        b[nt] = *reinterpret_cast<const bf16x8*>((const char*)Bs + Rn * 128 + ch * 16);
      }
#pragma unroll
      for (int mt = 0; mt < 4; ++mt)
#pragma unroll
        for (int nt = 0; nt < 4; ++nt)
          acc[mt][nt] = __builtin_amdgcn_mfma_f32_16x16x32_bf16(a[mt], b[nt],
                                                                acc[mt][nt], 0, 0, 0);
    }
  }

  float bv[4];
#pragma unroll
  for (int nt = 0; nt < 4; ++nt) bv[nt] = bin[col0 + wn * 64 + nt * 16 + lc];
#pragma unroll
  for (int mt = 0; mt < 4; ++mt) {
#pragma unroll
    for (int nt = 0; nt < 4; ++nt) {
      const int col = col0 + wn * 64 + nt * 16 + lc;
#pragma unroll
      for (int rr = 0; rr < 4; ++rr) {
        const int m = row0 + wm * 64 + mt * 16 + lg * 4 + rr;
        const size_t rowp = (size_t)(m & 63) * 512 + (m >> 6);  // [t][b]
        XG[rowp * G3 + col] = __float2bfloat16(acc[mt][nt][rr] + bv[nt]);
      }
    }
  }
}

// ---------------------------------------------------------------------------
// Kernel 2: persistent cooperative GRU scan.
// 256 blocks = 16 batch-groups (32 batches) x 16 col-groups (32 h-cols).
// U-slice (96 cols x 512 k, swizzled) resident in LDS for all 64 steps.
// Per step: stage h-slice (agent-atomic loads -> LDS), 192 MFMAs, gates
// in-register, h_new via agent-atomic stores, 16-block group barrier.
// ---------------------------------------------------------------------------
__global__ __launch_bounds__(256) void gru_scan_coop(
    const __hip_bfloat16* __restrict__ XG, const short* __restrict__ Upk,
    const float* __restrict__ brec, short* h_g, unsigned* bar,
    float* __restrict__ HT) {
  __shared__ __align__(16) short Us[96 * 512];  // 96 KB
  __shared__ __align__(16) short hS[32 * 512];  // 32 KB
  const int tid = threadIdx.x, w = tid >> 6, l = tid & 63;
  const int lc = l & 15, lg = l >> 4;
  const int bg = blockIdx.x >> 4, cgi = blockIdx.x & 15;
  const int b0 = bg * 32, c0 = cgi * 32;
  const int wm = w >> 1, wn = w & 1;

  // stage U slice once (pre-swizzled in global, linear LDS dest)
  {
    const short* src = Upk + (size_t)cgi * 49152;
#pragma unroll
    for (int r = 0; r < 24; ++r)
      gload_lds16(src + (r * 256 + tid) * 8, Us + (r * 256 + (tid & ~63)) * 8);
  }

  const int j = c0 + wn * 16 + lc;  // this lane's h/gate column
  const float brz = brec[j], brr = brec[512 + j], brh = brec[1024 + j];
  const int arow = wm * 16 + lc;
  const int ur0 = wn * 16 + lc;

  __syncthreads();  // Us staged

  for (int t = 0; t < TSTEPS; ++t) {
    // ---- stage h slice: agent-scope u64 loads -> LDS (linear copy) ----
    {
      const unsigned long long* hg64 =
          (const unsigned long long*)(h_g + (size_t)b0 * 512);
      unsigned long long v[16];
#pragma unroll
      for (int r = 0; r < 16; ++r)
        v[r] = __hip_atomic_load(hg64 + r * 256 + tid, __ATOMIC_RELAXED,
                                 __HIP_MEMORY_SCOPE_AGENT);
#pragma unroll
      for (int r = 0; r < 16; ++r)
        *(unsigned long long*)((char*)hS + (r * 256 + tid) * 8) = v[r];
    }
    // ---- xg loads for this step (independent of h) ----
    short xz[4], xr[4], xh[4];
#pragma unroll
    for (int r = 0; r < 4; ++r) {
      const int lb = wm * 16 + lg * 4 + r;
      const __hip_bfloat16* xp = XG + ((size_t)t * 512 + b0 + lb) * G3 + j;
      xz[r] = *(const short*)(xp);
      xr[r] = *(const short*)(xp + 512);
      xh[r] = *(const short*)(xp + 1024);
    }
    __syncthreads();  // hS ready

    // ---- hg = h @ U : 3 gate tiles, K=512 ----
    f32x4 za[3];
    za[0] = (f32x4){0.f, 0.f, 0.f, 0.f};
    za[1] = za[0]; za[2] = za[0];
#pragma unroll
    for (int kc = 0; kc < 16; ++kc) {
      const int sa = (kc * 4 + lg) ^ (arow & 7);
      const bf16x8 a =
          *(const bf16x8*)((const char*)hS + arow * 1024 + sa * 16);
#pragma unroll
      for (int g = 0; g < 3; ++g) {
        const int ur = g * 32 + ur0;
        const int sb = (kc * 4 + lg) ^ (ur & 7);
        const bf16x8 b =
            *(const bf16x8*)((const char*)Us + ur * 1024 + sb * 16);
        za[g] = __builtin_amdgcn_mfma_f32_16x16x32_bf16(a, b, za[g], 0, 0, 0);
      }
    }

    // ---- gates in-register; C/D: col=lane&15, row=(lane>>4)*4+reg ----
#pragma unroll
    for (int r = 0; r < 4; ++r) {
      const int lb = wm * 16 + lg * 4 + r;
      const float z = 1.f / (1.f + __expf(-(bf2f(xz[r]) + za[0][r] + brz)));
      const float rg = 1.f / (1.f + __expf(-(bf2f(xr[r]) + za[1][r] + brr)));
      const float hc = fmaxf(fmaf(rg, za[2][r] + brh, bf2f(xh[r])), 0.f);
      const int off = lb * 1024 + (((j >> 3) ^ (lb & 7)) << 4) + (j & 7) * 2;
      const float hold = bf2f(*(const short*)((const char*)hS + off));
      const float hnew = fmaf(z, hold - hc, hc);
      if (t < TSTEPS - 1) {
        __hip_atomic_store((unsigned short*)((char*)h_g + (size_t)b0 * 1024 + off),
                           (unsigned short)f2bf(hnew), __ATOMIC_RELAXED,
                           __HIP_MEMORY_SCOPE_AGENT);
      } else {
        HT[(size_t)(b0 + lb) * HID + j] = hnew;
      }
    }
    if (t == TSTEPS - 1) break;

    // ---- group barrier: 16 blocks sharing this batch-group ----
    __syncthreads();  // all stores in block complete (vmcnt drained)
    if (tid == 0) {
      __hip_atomic_fetch_add(&bar[bg], 1u, __ATOMIC_RELEASE,
                             __HIP_MEMORY_SCOPE_AGENT);
      const unsigned tgt = 16u * (unsigned)(t + 1);
      while (__hip_atomic_load(&bar[bg], __ATOMIC_ACQUIRE,
                               __HIP_MEMORY_SCOPE_AGENT) < tgt) {
        __builtin_amdgcn_s_sleep(2);
      }
    }
    __syncthreads();
  }
}

// ---------------------------------------------------------------------------
// Kernel 3: out = cat(hT,hT) @ W2 + b2 == hT @ (W2_top + W2_bot) + b2
// ---------------------------------------------------------------------------
__global__ __launch_bounds__(256) void final_proj(const float* __restrict__ HT,
                                                  const float* __restrict__ W2,
                                                  const float* __restrict__ b2,
                                                  float* __restrict__ OUT) {
  const int b = blockIdx.x >> 1;
  const int pp = ((blockIdx.x & 1) << 8) + threadIdx.x;
  float acc = b2[pp];
  const float* h = &HT[(size_t)b * HID];
  for (int k = 0; k < HID; ++k)
    acc = fmaf(h[k], W2[(size_t)k * POUT + pp] + W2[(size_t)(k + HID) * POUT + pp], acc);
  OUT[(size_t)b * POUT + pp] = acc;
}

// ---------------------------------------------------------------------------
extern "C" void kernel_launch(void* const* d_in, const int* in_sizes, int n_in,
                              void* d_out, int out_size, void* d_ws,
                              size_t ws_size, hipStream_t stream) {
  const float* X    = (const float*)d_in[0];
  const float* Win  = (const float*)d_in[1];
  const float* bin  = (const float*)d_in[2];
  const float* U    = (const float*)d_in[3];
  const float* brec = (const float*)d_in[4];
  const float* W2   = (const float*)d_in[5];
  const float* b2   = (const float*)d_in[6];
  float* OUT = (float*)d_out;

  char* ws = (char*)d_ws;
  size_t off = 0;
  __hip_bfloat16* XG = (__hip_bfloat16*)(ws + off); off += (size_t)MROWS * G3 * 2;   // 100.66 MB
  short* Wt   = (short*)(ws + off); off += (size_t)G3 * DIN * 2;                     // 3.15 MB
  short* Upk  = (short*)(ws + off); off += (size_t)G3 * HID * 2;                     // 1.57 MB
  float* HT   = (float*)(ws + off); off += (size_t)BATCH * HID * 4;                  // 1.05 MB
  short* h_g  = (short*)(ws + off); off += (size_t)BATCH * HID * 2;                  // 0.52 MB
  unsigned* bar = (unsigned*)(ws + off);                                             // 256 B

  // reset h0 = 0 and barrier counters (deterministic per call)
  hipMemsetAsync(h_g, 0, (size_t)BATCH * HID * 2 + 256, stream);

  transpose_cast<<<dim3(G3 / 32, DIN / 32), 256, 0, stream>>>(Win, Wt, DIN, G3);
  u_pack2<<<(16 * 96 * 512) / 256, 256, 0, stream>>>(U, Upk);
  gemm_xg_mfma<<<(MROWS / 128) * (G3 / 128), 256, 0, stream>>>(X, Wt, bin, XG);

  const __hip_bfloat16* XGc = XG;
  const short* Upkc = Upk;
  void* args[] = {(void*)&XGc, (void*)&Upkc, (void*)&brec,
                  (void*)&h_g, (void*)&bar, (void*)&HT};
  hipLaunchCooperativeKernel((const void*)gru_scan_coop, dim3(256), dim3(256),
                             args, 0, stream);

  final_proj<<<(BATCH * POUT) / 256, 256, 0, stream>>>(HT, W2, b2, OUT);
}

// Round 5
// 529.796 us; speedup vs baseline: 8.8972x; 2.7881x over previous
//
#include <hip/hip_runtime.h>
#include <hip/hip_bf16.h>
#include <stdint.h>

#define BATCH 512
#define TSTEPS 64
#define DIN 1024
#define HID 512
#define G3 1536
#define MROWS (BATCH * TSTEPS)
#define POUT 512

typedef __attribute__((ext_vector_type(8))) short bf16x8;
typedef __attribute__((ext_vector_type(4))) float f32x4;

__device__ __forceinline__ float bf2f(short s) {
  union { unsigned u; float f; } v;
  v.u = ((unsigned)(unsigned short)s) << 16;
  return v.f;
}
__device__ __forceinline__ short f2bf(float f) {
  __hip_bfloat16 h = __float2bfloat16(f);
  short s;
  __builtin_memcpy(&s, &h, 2);
  return s;
}
__device__ __forceinline__ void gload_lds16(const void* g, void* l) {
  __builtin_amdgcn_global_load_lds(
      (const __attribute__((address_space(1))) void*)g,
      (__attribute__((address_space(3))) void*)l, 16, 0, 0);
}

// ---------------------------------------------------------------------------
// transpose + fp32->bf16 cast: out[c][r] = bf16(in[r][c])  (for W_in -> Wt)
// ---------------------------------------------------------------------------
__global__ __launch_bounds__(256) void transpose_cast(const float* __restrict__ in,
                                                      short* __restrict__ out,
                                                      int R, int C) {
  __shared__ float tile[32][33];
  const int c0 = blockIdx.x * 32, r0 = blockIdx.y * 32;
  const int tx = threadIdx.x & 31, ty = threadIdx.x >> 5;
#pragma unroll
  for (int i = 0; i < 4; ++i) {
    const int r = r0 + ty + i * 8;
    tile[ty + i * 8][tx] = in[(size_t)r * C + c0 + tx];
  }
  __syncthreads();
#pragma unroll
  for (int i = 0; i < 4; ++i) {
    const int c = c0 + ty + i * 8;
    out[(size_t)c * R + r0 + tx] = f2bf(tile[tx][ty + i * 8]);
  }
}

// ---------------------------------------------------------------------------
// Pack U (fp32 [512][1536]) -> Upk bf16 [16 cg][96 ur][64 slot][8 e];
// slot holds logical k-chunk (slot ^ (ur&7)) -- XOR swizzle pre-applied so
// the scan stages it LINEARLY with global_load_lds.
// ---------------------------------------------------------------------------
__global__ __launch_bounds__(256) void u_pack2(const float* __restrict__ U,
                                               short* __restrict__ Upk) {
  const unsigned idx = blockIdx.x * 256 + threadIdx.x;  // < 786432
  const unsigned cg = idx / 49152u;
  const unsigned rem = idx - cg * 49152u;
  const unsigned ur = rem >> 9;
  const unsigned r2 = rem & 511u;
  const unsigned s = r2 >> 3, e = r2 & 7u;
  const unsigned chunk = s ^ (ur & 7u);
  const unsigned k = chunk * 8u + e;
  const unsigned g = ur >> 5, cc = ur & 31u;
  const unsigned col = g * 512u + cg * 32u + cc;
  Upk[idx] = f2bf(U[(size_t)k * G3 + col]);
}

// ---------------------------------------------------------------------------
// Kernel 1: XG = bf16(X @ W_in + b_in), MFMA 128x128 BK=64.
// Output layout: XG[t*512 + b][1536]
// ---------------------------------------------------------------------------
__global__ __launch_bounds__(256) void gemm_xg_mfma(const float* __restrict__ X,
                                                    const short* __restrict__ Wt,
                                                    const float* __restrict__ bin,
                                                    __hip_bfloat16* __restrict__ XG) {
  __shared__ __align__(16) short As[128 * 64];
  __shared__ __align__(16) short Bs[128 * 64];
  const int tid = threadIdx.x;
  const int w = tid >> 6, l = tid & 63;
  const int lc = l & 15, lg = l >> 4;

  const int nwg = gridDim.x;
  const int wg = (blockIdx.x & 7) * (nwg >> 3) + (blockIdx.x >> 3);
  const int rt = wg & 255, ct = wg >> 8;
  const int row0 = rt * 128, col0 = ct * 128;

  const int wm = w >> 1, wn = w & 1;

  f32x4 acc[4][4];
#pragma unroll
  for (int mt = 0; mt < 4; ++mt)
#pragma unroll
    for (int nt = 0; nt < 4; ++nt) acc[mt][nt] = (f32x4){0.f, 0.f, 0.f, 0.f};

  const int tr = tid >> 3, p = tid & 7;

  for (int k0 = 0; k0 < DIN; k0 += 64) {
    float4 ar[4][2];
#pragma unroll
    for (int i = 0; i < 4; ++i) {
      const int r = i * 32 + tr;
      const int s = p ^ (r & 7);
      const float* xp = &X[(size_t)(row0 + r) * DIN + k0 + s * 8];
      ar[i][0] = *reinterpret_cast<const float4*>(xp);
      ar[i][1] = *reinterpret_cast<const float4*>(xp + 4);
    }
    __syncthreads();
#pragma unroll
    for (int i = 0; i < 4; ++i) {
      const int r = i * 32 + tr;
      bf16x8 v;
      v[0] = f2bf(ar[i][0].x); v[1] = f2bf(ar[i][0].y);
      v[2] = f2bf(ar[i][0].z); v[3] = f2bf(ar[i][0].w);
      v[4] = f2bf(ar[i][1].x); v[5] = f2bf(ar[i][1].y);
      v[6] = f2bf(ar[i][1].z); v[7] = f2bf(ar[i][1].w);
      *reinterpret_cast<bf16x8*>((char*)As + r * 128 + p * 16) = v;
    }
#pragma unroll
    for (int i = 0; i < 4; ++i) {
      const int rr = w * 32 + i * 8 + (l >> 3);
      const int pp = l & 7;
      const int s = pp ^ (rr & 7);
      gload_lds16(&Wt[(size_t)(col0 + rr) * DIN + k0 + s * 8],
                  (char*)Bs + (w * 32 + i * 8) * 128);
    }
    __syncthreads();
#pragma unroll
    for (int kc = 0; kc < 2; ++kc) {
      bf16x8 a[4], b[4];
#pragma unroll
      for (int mt = 0; mt < 4; ++mt) {
        const int R = wm * 64 + mt * 16 + lc;
        const int ch = (kc * 4 + lg) ^ (R & 7);
        a[mt] = *reinterpret_cast<const bf16x8*>((const char*)As + R * 128 + ch * 16);
      }
#pragma unroll
      for (int nt = 0; nt < 4; ++nt) {
        const int Rn = wn * 64 + nt * 16 + lc;
        const int ch = (kc * 4 + lg) ^ (Rn & 7);
        b[nt] = *reinterpret_cast<const bf16x8*>((const char*)Bs + Rn * 128 + ch * 16);
      }
#pragma unroll
      for (int mt = 0; mt < 4; ++mt)
#pragma unroll
        for (int nt = 0; nt < 4; ++nt)
          acc[mt][nt] = __builtin_amdgcn_mfma_f32_16x16x32_bf16(a[mt], b[nt],
                                                                acc[mt][nt], 0, 0, 0);
    }
  }

  float bv[4];
#pragma unroll
  for (int nt = 0; nt < 4; ++nt) bv[nt] = bin[col0 + wn * 64 + nt * 16 + lc];
#pragma unroll
  for (int mt = 0; mt < 4; ++mt) {
#pragma unroll
    for (int nt = 0; nt < 4; ++nt) {
      const int col = col0 + wn * 64 + nt * 16 + lc;
#pragma unroll
      for (int rr = 0; rr < 4; ++rr) {
        const int m = row0 + wm * 64 + mt * 16 + lg * 4 + rr;
        const size_t rowp = (size_t)(m & 63) * 512 + (m >> 6);  // [t][b]
        XG[rowp * G3 + col] = __float2bfloat16(acc[mt][nt][rr] + bv[nt]);
      }
    }
  }
}

// ---------------------------------------------------------------------------
// Kernel 2: persistent cooperative GRU scan.
// 256 blocks = 16 batch-groups x 16 col-groups. U-slice resident in LDS.
// RELAXED-only protocol (agent atomics are sc0/sc1 cache-bypassing; no
// acq/rel fences -> no buffer_wbl2/buffer_inv L2 nukes). h_g double-buffered
// by t-parity (race-free with one barrier/step). xg staged per step via
// linear global_load_lds, double-buffered, issued during the barrier wait.
// ---------------------------------------------------------------------------
__global__ __launch_bounds__(256) void gru_scan_coop(
    const __hip_bfloat16* __restrict__ XG, const short* __restrict__ Upk,
    const float* __restrict__ brec, short* h_g, unsigned* bar,
    float* __restrict__ HT) {
  __shared__ __align__(16) short Us[96 * 512];   // 96 KB
  __shared__ __align__(16) short hS[32 * 512];   // 32 KB
  __shared__ __align__(16) short xgL[2][3072];   // 12 KB
  const int tid = threadIdx.x, w = tid >> 6, l = tid & 63;
  const int lc = l & 15, lg = l >> 4;
  const int bg = blockIdx.x >> 4, cgi = blockIdx.x & 15;
  const int b0 = bg * 32, c0 = cgi * 32;
  const int wm = w >> 1, wn = w & 1;

  // stage U slice once (pre-swizzled global, linear LDS dest)
  {
    const short* usrc = Upk + (size_t)cgi * 49152;
#pragma unroll
    for (int r = 0; r < 24; ++r)
      gload_lds16(usrc + (r * 256 + tid) * 8, Us + (r * 256 + (tid & ~63)) * 8);
  }
  // zero hS (t=0 computes with h=0; no h_g read at t=0)
  for (int i = tid; i < 4096; i += 256) ((unsigned long long*)hS)[i] = 0ull;

  // per-thread xg staging slots (t-invariant). 16B chunk i <-> (b_l,g,c8):
  // i = b_l*12 + g*4 + c8 ; LDS layout [32 b][3 g][32 cc] bf16 (6144 B)
  const int i0 = tid;
  const int bl0 = i0 / 12, q0 = i0 - bl0 * 12;
  const int off0 = bl0 * 1536 + (q0 >> 2) * 512 + c0 + (q0 & 3) * 8;
  const int i1 = 256 + tid;  // used by tid<128 (waves 0,1)
  const int bl1 = i1 / 12, q1 = i1 - bl1 * 12;
  const int off1 = bl1 * 1536 + (q1 >> 2) * 512 + c0 + (q1 & 3) * 8;

  const short* XGs = (const short*)XG;
  {  // stage xg(t=0) into xgL[0]
    const short* xs = XGs + (size_t)b0 * 1536;
    gload_lds16(xs + off0, (char*)xgL + w * 1024);
    if (tid < 128) gload_lds16(xs + off1, (char*)xgL + 4096 + w * 1024);
  }

  const int j = c0 + wn * 16 + lc;  // this lane's h/gate column
  const float brz = brec[j], brr = brec[512 + j], brh = brec[1024 + j];
  const int arow = wm * 16 + lc;
  const int ur0 = wn * 16 + lc;

  __syncthreads();  // Us, hS, xg(0) ready

  for (int t = 0; t < TSTEPS; ++t) {
    if (t > 0) {
      // stage h slice from buffer (t&1): relaxed agent atomics (IF-coherent)
      const unsigned long long* hsrc = (const unsigned long long*)(
          h_g + ((size_t)(t & 1) * BATCH + b0) * 512);
      unsigned long long v[16];
#pragma unroll
      for (int r = 0; r < 16; ++r)
        v[r] = __hip_atomic_load(hsrc + r * 256 + tid, __ATOMIC_RELAXED,
                                 __HIP_MEMORY_SCOPE_AGENT);
#pragma unroll
      for (int r = 0; r < 16; ++r)
        ((unsigned long long*)hS)[r * 256 + tid] = v[r];
      __syncthreads();  // hS ready
    }

    // hg = h @ U : 3 gate tiles, K=512 (swizzled LDS, conflict-free b128)
    f32x4 za0 = (f32x4){0.f, 0.f, 0.f, 0.f}, za1 = za0, za2 = za0;
#pragma unroll
    for (int kc = 0; kc < 16; ++kc) {
      const int s = kc * 4 + lg;
      const bf16x8 a = *(const bf16x8*)((const char*)hS + arow * 1024 +
                                        (s ^ (arow & 7)) * 16);
      const char* ub =
          (const char*)Us + ur0 * 1024 + (s ^ (ur0 & 7)) * 16;  // (ur&7) same all g
      const bf16x8 bz = *(const bf16x8*)(ub);
      const bf16x8 brg = *(const bf16x8*)(ub + 32 * 1024);
      const bf16x8 bh = *(const bf16x8*)(ub + 64 * 1024);
      za0 = __builtin_amdgcn_mfma_f32_16x16x32_bf16(a, bz, za0, 0, 0, 0);
      za1 = __builtin_amdgcn_mfma_f32_16x16x32_bf16(a, brg, za1, 0, 0, 0);
      za2 = __builtin_amdgcn_mfma_f32_16x16x32_bf16(a, bh, za2, 0, 0, 0);
    }

    // gates in-register; C/D: col=lane&15, row=(lane>>4)*4+reg
    const short* xb = xgL[t & 1];
#pragma unroll
    for (int r = 0; r < 4; ++r) {
      const int lb = wm * 16 + lg * 4 + r;
      const float xz = bf2f(xb[lb * 96 + wn * 16 + lc]);
      const float xr = bf2f(xb[lb * 96 + 32 + wn * 16 + lc]);
      const float xh = bf2f(xb[lb * 96 + 64 + wn * 16 + lc]);
      const float z = 1.f / (1.f + __expf(-(xz + za0[r] + brz)));
      const float rg = 1.f / (1.f + __expf(-(xr + za1[r] + brr)));
      const float hc = fmaxf(fmaf(rg, za2[r] + brh, xh), 0.f);
      const int hoff = lb * 1024 + (((j >> 3) ^ (lb & 7)) << 4) + (j & 7) * 2;
      const float hold = bf2f(*(const short*)((const char*)hS + hoff));
      const float hnew = fmaf(z, hold - hc, hc);
      if (t == TSTEPS - 1) {
        HT[(size_t)(b0 + lb) * HID + j] = hnew;
      } else {
        __hip_atomic_store(
            (unsigned short*)((char*)h_g +
                              ((size_t)((t + 1) & 1) * BATCH + b0) * 1024 + hoff),
            (unsigned short)f2bf(hnew), __ATOMIC_RELAXED,
            __HIP_MEMORY_SCOPE_AGENT);
      }
    }
    if (t == TSTEPS - 1) break;

    __syncthreads();  // vmcnt(0) drain: h stores at IF before counter add
    if (tid == 0)
      __hip_atomic_fetch_add(&bar[bg * 32], 1u, __ATOMIC_RELAXED,
                             __HIP_MEMORY_SCOPE_AGENT);
    {  // stage xg(t+1) while the barrier propagates
      const short* xs = XGs + ((size_t)(t + 1) * 512 + b0) * 1536;
      char* xd = (char*)xgL + ((t + 1) & 1) * 6144;
      gload_lds16(xs + off0, xd + w * 1024);
      if (tid < 128) gload_lds16(xs + off1, xd + 4096 + w * 1024);
    }
    if (tid == 0) {
      const unsigned tgt = 16u * (unsigned)(t + 1);
      while (__hip_atomic_load(&bar[bg * 32], __ATOMIC_RELAXED,
                               __HIP_MEMORY_SCOPE_AGENT) < tgt)
        __builtin_amdgcn_s_sleep(2);
    }
    __syncthreads();
  }
}

// ---------------------------------------------------------------------------
// Kernel 3: out = cat(hT,hT) @ W2 + b2 == hT @ (W2_top + W2_bot) + b2
// ---------------------------------------------------------------------------
__global__ __launch_bounds__(256) void final_proj(const float* __restrict__ HT,
                                                  const float* __restrict__ W2,
                                                  const float* __restrict__ b2,
                                                  float* __restrict__ OUT) {
  const int b = blockIdx.x >> 1;
  const int pp = ((blockIdx.x & 1) << 8) + threadIdx.x;
  float acc = b2[pp];
  const float* h = &HT[(size_t)b * HID];
  for (int k = 0; k < HID; ++k)
    acc = fmaf(h[k], W2[(size_t)k * POUT + pp] + W2[(size_t)(k + HID) * POUT + pp], acc);
  OUT[(size_t)b * POUT + pp] = acc;
}

// ---------------------------------------------------------------------------
extern "C" void kernel_launch(void* const* d_in, const int* in_sizes, int n_in,
                              void* d_out, int out_size, void* d_ws,
                              size_t ws_size, hipStream_t stream) {
  const float* X    = (const float*)d_in[0];
  const float* Win  = (const float*)d_in[1];
  const float* bin  = (const float*)d_in[2];
  const float* U    = (const float*)d_in[3];
  const float* brec = (const float*)d_in[4];
  const float* W2   = (const float*)d_in[5];
  const float* b2   = (const float*)d_in[6];
  float* OUT = (float*)d_out;

  char* ws = (char*)d_ws;
  size_t off = 0;
  __hip_bfloat16* XG = (__hip_bfloat16*)(ws + off); off += (size_t)MROWS * G3 * 2;  // 100.66 MB
  short* Wt   = (short*)(ws + off); off += (size_t)G3 * DIN * 2;                    // 3.15 MB
  short* Upk  = (short*)(ws + off); off += (size_t)G3 * HID * 2;                    // 1.57 MB
  float* HT   = (float*)(ws + off); off += (size_t)BATCH * HID * 4;                 // 1.05 MB
  short* h_g  = (short*)(ws + off); off += (size_t)2 * BATCH * HID * 2;             // 1.05 MB (dbuf)
  unsigned* bar = (unsigned*)(ws + off);                                            // 2 KB

  hipMemsetAsync(bar, 0, 2048, stream);  // barrier counters only; h_g[1] is
                                         // fully written at t=0 before any read

  transpose_cast<<<dim3(G3 / 32, DIN / 32), 256, 0, stream>>>(Win, Wt, DIN, G3);
  u_pack2<<<(16 * 96 * 512) / 256, 256, 0, stream>>>(U, Upk);
  gemm_xg_mfma<<<(MROWS / 128) * (G3 / 128), 256, 0, stream>>>(X, Wt, bin, XG);

  const __hip_bfloat16* XGc = XG;
  const short* Upkc = Upk;
  void* args[] = {(void*)&XGc, (void*)&Upkc, (void*)&brec,
                  (void*)&h_g, (void*)&bar, (void*)&HT};
  hipLaunchCooperativeKernel((const void*)gru_scan_coop, dim3(256), dim3(256),
                             args, 0, stream);

  final_proj<<<(BATCH * POUT) / 256, 256, 0, stream>>>(HT, W2, b2, OUT);
}

// Round 6
// 473.837 us; speedup vs baseline: 9.9479x; 1.1181x over previous
//
#include <hip/hip_runtime.h>
#include <hip/hip_bf16.h>
#include <stdint.h>

#define BATCH 512
#define TSTEPS 64
#define DIN 1024
#define HID 512
#define G3 1536
#define MROWS (BATCH * TSTEPS)
#define POUT 512

typedef __attribute__((ext_vector_type(8))) short bf16x8;
typedef __attribute__((ext_vector_type(4))) float f32x4;

__device__ __forceinline__ float bf2f(short s) {
  union { unsigned u; float f; } v;
  v.u = ((unsigned)(unsigned short)s) << 16;
  return v.f;
}
__device__ __forceinline__ short f2bf(float f) {
  __hip_bfloat16 h = __float2bfloat16(f);
  short s;
  __builtin_memcpy(&s, &h, 2);
  return s;
}
__device__ __forceinline__ void gload_lds16(const void* g, void* l) {
  __builtin_amdgcn_global_load_lds(
      (const __attribute__((address_space(1))) void*)g,
      (__attribute__((address_space(3))) void*)l, 16, 0, 0);
}

// ---------------------------------------------------------------------------
// transpose + fp32->bf16 cast: out[c][r] = bf16(in[r][c])  (for W_in -> Wt)
// ---------------------------------------------------------------------------
__global__ __launch_bounds__(256) void transpose_cast(const float* __restrict__ in,
                                                      short* __restrict__ out,
                                                      int R, int C) {
  __shared__ float tile[32][33];
  const int c0 = blockIdx.x * 32, r0 = blockIdx.y * 32;
  const int tx = threadIdx.x & 31, ty = threadIdx.x >> 5;
#pragma unroll
  for (int i = 0; i < 4; ++i) {
    const int r = r0 + ty + i * 8;
    tile[ty + i * 8][tx] = in[(size_t)r * C + c0 + tx];
  }
  __syncthreads();
#pragma unroll
  for (int i = 0; i < 4; ++i) {
    const int c = c0 + ty + i * 8;
    out[(size_t)c * R + r0 + tx] = f2bf(tile[tx][ty + i * 8]);
  }
}

// ---------------------------------------------------------------------------
// Pack U (fp32 [512][1536]) -> Upk bf16 [16 cg][96 ur][64 slot][8 e];
// slot holds logical k-chunk (slot ^ (ur&7)) -- XOR swizzle pre-applied so
// the scan stages it LINEARLY with global_load_lds.
// ---------------------------------------------------------------------------
__global__ __launch_bounds__(256) void u_pack2(const float* __restrict__ U,
                                               short* __restrict__ Upk) {
  const unsigned idx = blockIdx.x * 256 + threadIdx.x;  // < 786432
  const unsigned cg = idx / 49152u;
  const unsigned rem = idx - cg * 49152u;
  const unsigned ur = rem >> 9;
  const unsigned r2 = rem & 511u;
  const unsigned s = r2 >> 3, e = r2 & 7u;
  const unsigned chunk = s ^ (ur & 7u);
  const unsigned k = chunk * 8u + e;
  const unsigned g = ur >> 5, cc = ur & 31u;
  const unsigned col = g * 512u + cg * 32u + cc;
  Upk[idx] = f2bf(U[(size_t)k * G3 + col]);
}

// ---------------------------------------------------------------------------
// Kernel 1: XG = bf16(X @ W_in + b_in), MFMA 128x128 BK=64.
// Output layout: XG[t*512 + b][1536].
// Tile order: each XCD owns a contiguous wg chunk; within a chunk the 12
// column tiles of one row-panel are consecutive -> A panel fetched from HBM
// once (11 L2 re-hits), B (3 MB) L2-resident.
// ---------------------------------------------------------------------------
__global__ __launch_bounds__(256) void gemm_xg_mfma(const float* __restrict__ X,
                                                    const short* __restrict__ Wt,
                                                    const float* __restrict__ bin,
                                                    __hip_bfloat16* __restrict__ XG) {
  __shared__ __align__(16) short As[128 * 64];
  __shared__ __align__(16) short Bs[128 * 64];
  const int tid = threadIdx.x;
  const int w = tid >> 6, l = tid & 63;
  const int lc = l & 15, lg = l >> 4;

  const int xcd = blockIdx.x & 7;
  const int idx = blockIdx.x >> 3;          // 0..383
  const int wg = xcd * 384 + idx;           // contiguous chunk per XCD
  const int rt = wg / 12, ct = wg % 12;     // 12 consecutive share row-panel
  const int row0 = rt * 128, col0 = ct * 128;

  const int wm = w >> 1, wn = w & 1;

  f32x4 acc[4][4];
#pragma unroll
  for (int mt = 0; mt < 4; ++mt)
#pragma unroll
    for (int nt = 0; nt < 4; ++nt) acc[mt][nt] = (f32x4){0.f, 0.f, 0.f, 0.f};

  const int tr = tid >> 3, p = tid & 7;

  for (int k0 = 0; k0 < DIN; k0 += 64) {
    float4 ar[4][2];
#pragma unroll
    for (int i = 0; i < 4; ++i) {
      const int r = i * 32 + tr;
      const int s = p ^ (r & 7);
      const float* xp = &X[(size_t)(row0 + r) * DIN + k0 + s * 8];
      ar[i][0] = *reinterpret_cast<const float4*>(xp);
      ar[i][1] = *reinterpret_cast<const float4*>(xp + 4);
    }
    __syncthreads();
#pragma unroll
    for (int i = 0; i < 4; ++i) {
      const int r = i * 32 + tr;
      bf16x8 v;
      v[0] = f2bf(ar[i][0].x); v[1] = f2bf(ar[i][0].y);
      v[2] = f2bf(ar[i][0].z); v[3] = f2bf(ar[i][0].w);
      v[4] = f2bf(ar[i][1].x); v[5] = f2bf(ar[i][1].y);
      v[6] = f2bf(ar[i][1].z); v[7] = f2bf(ar[i][1].w);
      *reinterpret_cast<bf16x8*>((char*)As + r * 128 + p * 16) = v;
    }
#pragma unroll
    for (int i = 0; i < 4; ++i) {
      const int rr = w * 32 + i * 8 + (l >> 3);
      const int pp = l & 7;
      const int s = pp ^ (rr & 7);
      gload_lds16(&Wt[(size_t)(col0 + rr) * DIN + k0 + s * 8],
                  (char*)Bs + (w * 32 + i * 8) * 128);
    }
    __syncthreads();
#pragma unroll
    for (int kc = 0; kc < 2; ++kc) {
      bf16x8 a[4], b[4];
#pragma unroll
      for (int mt = 0; mt < 4; ++mt) {
        const int R = wm * 64 + mt * 16 + lc;
        const int ch = (kc * 4 + lg) ^ (R & 7);
        a[mt] = *reinterpret_cast<const bf16x8*>((const char*)As + R * 128 + ch * 16);
      }
#pragma unroll
      for (int nt = 0; nt < 4; ++nt) {
        const int Rn = wn * 64 + nt * 16 + lc;
        const int ch = (kc * 4 + lg) ^ (Rn & 7);
        b[nt] = *reinterpret_cast<const bf16x8*>((const char*)Bs + Rn * 128 + ch * 16);
      }
#pragma unroll
      for (int mt = 0; mt < 4; ++mt)
#pragma unroll
        for (int nt = 0; nt < 4; ++nt)
          acc[mt][nt] = __builtin_amdgcn_mfma_f32_16x16x32_bf16(a[mt], b[nt],
                                                                acc[mt][nt], 0, 0, 0);
    }
  }

  float bv[4];
#pragma unroll
  for (int nt = 0; nt < 4; ++nt) bv[nt] = bin[col0 + wn * 64 + nt * 16 + lc];
#pragma unroll
  for (int mt = 0; mt < 4; ++mt) {
#pragma unroll
    for (int nt = 0; nt < 4; ++nt) {
      const int col = col0 + wn * 64 + nt * 16 + lc;
#pragma unroll
      for (int rr = 0; rr < 4; ++rr) {
        const int m = row0 + wm * 64 + mt * 16 + lg * 4 + rr;
        const size_t rowp = (size_t)(m & 63) * 512 + (m >> 6);  // [t][b]
        XG[rowp * G3 + col] = __float2bfloat16(acc[mt][nt][rr] + bv[nt]);
      }
    }
  }
}

// ---------------------------------------------------------------------------
// Kernel 2: persistent cooperative GRU scan.
// 256 blocks = 16 batch-groups x 16 col-groups. U-slice resident in LDS.
// RELAXED-only protocol; h_g double-buffered by t-parity. Group barrier via
// per-block flag slots (no RMW serialization): block (bg,cg) stores t+1 to
// bar[bg*16+cg]; 16 lanes of wave 0 each spin on one slot (one 64B line).
// ---------------------------------------------------------------------------
__global__ __launch_bounds__(256) void gru_scan_coop(
    const __hip_bfloat16* __restrict__ XG, const short* __restrict__ Upk,
    const float* __restrict__ brec, short* h_g, unsigned* bar,
    float* __restrict__ HT) {
  __shared__ __align__(16) short Us[96 * 512];   // 96 KB
  __shared__ __align__(16) short hS[32 * 512];   // 32 KB
  __shared__ __align__(16) short xgL[2][3072];   // 12 KB
  const int tid = threadIdx.x, w = tid >> 6, l = tid & 63;
  const int lc = l & 15, lg = l >> 4;
  const int bg = blockIdx.x >> 4, cgi = blockIdx.x & 15;
  const int b0 = bg * 32, c0 = cgi * 32;
  const int wm = w >> 1, wn = w & 1;

  // stage U slice once (pre-swizzled global, linear LDS dest)
  {
    const short* usrc = Upk + (size_t)cgi * 49152;
#pragma unroll
    for (int r = 0; r < 24; ++r)
      gload_lds16(usrc + (r * 256 + tid) * 8, Us + (r * 256 + (tid & ~63)) * 8);
  }
  // zero hS (t=0 computes with h=0; no h_g read at t=0)
  for (int i = tid; i < 4096; i += 256) ((unsigned long long*)hS)[i] = 0ull;

  // per-thread xg staging slots (t-invariant). 16B chunk i <-> (b_l,g,c8):
  // i = b_l*12 + g*4 + c8 ; LDS layout [32 b][3 g][32 cc] bf16 (6144 B)
  const int i0 = tid;
  const int bl0 = i0 / 12, q0 = i0 - bl0 * 12;
  const int off0 = bl0 * 1536 + (q0 >> 2) * 512 + c0 + (q0 & 3) * 8;
  const int i1 = 256 + tid;  // used by tid<128 (waves 0,1)
  const int bl1 = i1 / 12, q1 = i1 - bl1 * 12;
  const int off1 = bl1 * 1536 + (q1 >> 2) * 512 + c0 + (q1 & 3) * 8;

  const short* XGs = (const short*)XG;
  {  // stage xg(t=0) into xgL[0]
    const short* xs = XGs + (size_t)b0 * 1536;
    gload_lds16(xs + off0, (char*)xgL + w * 1024);
    if (tid < 128) gload_lds16(xs + off1, (char*)xgL + 4096 + w * 1024);
  }

  const int j = c0 + wn * 16 + lc;  // this lane's h/gate column
  const float brz = brec[j], brr = brec[512 + j], brh = brec[1024 + j];
  const int arow = wm * 16 + lc;
  const int ur0 = wn * 16 + lc;

  __syncthreads();  // Us, hS, xg(0) ready

  for (int t = 0; t < TSTEPS; ++t) {
    if (t > 0) {
      // stage h slice from buffer (t&1): relaxed agent atomics (IF-coherent)
      const unsigned long long* hsrc = (const unsigned long long*)(
          h_g + ((size_t)(t & 1) * BATCH + b0) * 512);
      unsigned long long v[16];
#pragma unroll
      for (int r = 0; r < 16; ++r)
        v[r] = __hip_atomic_load(hsrc + r * 256 + tid, __ATOMIC_RELAXED,
                                 __HIP_MEMORY_SCOPE_AGENT);
#pragma unroll
      for (int r = 0; r < 16; ++r)
        ((unsigned long long*)hS)[r * 256 + tid] = v[r];
      __syncthreads();  // hS ready
    }

    // hg = h @ U : 3 gate tiles, K=512 (swizzled LDS, conflict-free b128)
    f32x4 za0 = (f32x4){0.f, 0.f, 0.f, 0.f}, za1 = za0, za2 = za0;
#pragma unroll
    for (int kc = 0; kc < 16; ++kc) {
      const int s = kc * 4 + lg;
      const bf16x8 a = *(const bf16x8*)((const char*)hS + arow * 1024 +
                                        (s ^ (arow & 7)) * 16);
      const char* ub =
          (const char*)Us + ur0 * 1024 + (s ^ (ur0 & 7)) * 16;
      const bf16x8 bz = *(const bf16x8*)(ub);
      const bf16x8 brg = *(const bf16x8*)(ub + 32 * 1024);
      const bf16x8 bh = *(const bf16x8*)(ub + 64 * 1024);
      za0 = __builtin_amdgcn_mfma_f32_16x16x32_bf16(a, bz, za0, 0, 0, 0);
      za1 = __builtin_amdgcn_mfma_f32_16x16x32_bf16(a, brg, za1, 0, 0, 0);
      za2 = __builtin_amdgcn_mfma_f32_16x16x32_bf16(a, bh, za2, 0, 0, 0);
    }

    // gates in-register; C/D: col=lane&15, row=(lane>>4)*4+reg
    const short* xb = xgL[t & 1];
#pragma unroll
    for (int r = 0; r < 4; ++r) {
      const int lb = wm * 16 + lg * 4 + r;
      const float xz = bf2f(xb[lb * 96 + wn * 16 + lc]);
      const float xr = bf2f(xb[lb * 96 + 32 + wn * 16 + lc]);
      const float xh = bf2f(xb[lb * 96 + 64 + wn * 16 + lc]);
      const float z = 1.f / (1.f + __expf(-(xz + za0[r] + brz)));
      const float rg = 1.f / (1.f + __expf(-(xr + za1[r] + brr)));
      const float hc = fmaxf(fmaf(rg, za2[r] + brh, xh), 0.f);
      const int hoff = lb * 1024 + (((j >> 3) ^ (lb & 7)) << 4) + (j & 7) * 2;
      const float hold = bf2f(*(const short*)((const char*)hS + hoff));
      const float hnew = fmaf(z, hold - hc, hc);
      if (t == TSTEPS - 1) {
        HT[(size_t)(b0 + lb) * HID + j] = hnew;
      } else {
        __hip_atomic_store(
            (unsigned short*)((char*)h_g +
                              ((size_t)((t + 1) & 1) * BATCH + b0) * 1024 + hoff),
            (unsigned short)f2bf(hnew), __ATOMIC_RELAXED,
            __HIP_MEMORY_SCOPE_AGENT);
      }
    }
    if (t == TSTEPS - 1) break;

    __syncthreads();  // vmcnt(0) drain: h stores visible before flag store
    if (tid == 0)
      __hip_atomic_store(&bar[bg * 16 + cgi], (unsigned)(t + 1),
                         __ATOMIC_RELAXED, __HIP_MEMORY_SCOPE_AGENT);
    {  // stage xg(t+1) while the flags propagate
      const short* xs = XGs + ((size_t)(t + 1) * 512 + b0) * 1536;
      char* xd = (char*)xgL + ((t + 1) & 1) * 6144;
      gload_lds16(xs + off0, xd + w * 1024);
      if (tid < 128) gload_lds16(xs + off1, xd + 4096 + w * 1024);
    }
    if (w == 0 && l < 16) {  // lane l watches slot l (one 64B line)
      while (__hip_atomic_load(&bar[bg * 16 + l], __ATOMIC_RELAXED,
                               __HIP_MEMORY_SCOPE_AGENT) < (unsigned)(t + 1))
        __builtin_amdgcn_s_sleep(1);
    }
    __syncthreads();
  }
}

// ---------------------------------------------------------------------------
// Kernel 3: out = cat(hT,hT) @ W2 + b2 == hT @ (W2_top + W2_bot) + b2
// ---------------------------------------------------------------------------
__global__ __launch_bounds__(256) void final_proj(const float* __restrict__ HT,
                                                  const float* __restrict__ W2,
                                                  const float* __restrict__ b2,
                                                  float* __restrict__ OUT) {
  const int b = blockIdx.x >> 1;
  const int pp = ((blockIdx.x & 1) << 8) + threadIdx.x;
  float acc = b2[pp];
  const float* h = &HT[(size_t)b * HID];
  for (int k = 0; k < HID; ++k)
    acc = fmaf(h[k], W2[(size_t)k * POUT + pp] + W2[(size_t)(k + HID) * POUT + pp], acc);
  OUT[(size_t)b * POUT + pp] = acc;
}

// ---------------------------------------------------------------------------
extern "C" void kernel_launch(void* const* d_in, const int* in_sizes, int n_in,
                              void* d_out, int out_size, void* d_ws,
                              size_t ws_size, hipStream_t stream) {
  const float* X    = (const float*)d_in[0];
  const float* Win  = (const float*)d_in[1];
  const float* bin  = (const float*)d_in[2];
  const float* U    = (const float*)d_in[3];
  const float* brec = (const float*)d_in[4];
  const float* W2   = (const float*)d_in[5];
  const float* b2   = (const float*)d_in[6];
  float* OUT = (float*)d_out;

  char* ws = (char*)d_ws;
  size_t off = 0;
  __hip_bfloat16* XG = (__hip_bfloat16*)(ws + off); off += (size_t)MROWS * G3 * 2;  // 100.66 MB
  short* Wt   = (short*)(ws + off); off += (size_t)G3 * DIN * 2;                    // 3.15 MB
  short* Upk  = (short*)(ws + off); off += (size_t)G3 * HID * 2;                    // 1.57 MB
  float* HT   = (float*)(ws + off); off += (size_t)BATCH * HID * 4;                 // 1.05 MB
  short* h_g  = (short*)(ws + off); off += (size_t)2 * BATCH * HID * 2;             // 1.05 MB (dbuf)
  unsigned* bar = (unsigned*)(ws + off);                                            // 1 KB

  hipMemsetAsync(bar, 0, 1024, stream);  // flag slots; h_g needs no reset
                                         // (each parity buffer fully written
                                         // before first read every call)

  transpose_cast<<<dim3(G3 / 32, DIN / 32), 256, 0, stream>>>(Win, Wt, DIN, G3);
  u_pack2<<<(16 * 96 * 512) / 256, 256, 0, stream>>>(U, Upk);
  gemm_xg_mfma<<<(MROWS / 128) * (G3 / 128), 256, 0, stream>>>(X, Wt, bin, XG);

  const __hip_bfloat16* XGc = XG;
  const short* Upkc = Upk;
  void* args[] = {(void*)&XGc, (void*)&Upkc, (void*)&brec,
                  (void*)&h_g, (void*)&bar, (void*)&HT};
  hipLaunchCooperativeKernel((const void*)gru_scan_coop, dim3(256), dim3(256),
                             args, 0, stream);

  final_proj<<<(BATCH * POUT) / 256, 256, 0, stream>>>(HT, W2, b2, OUT);
}